// Round 1
// baseline (98.452 us; speedup 1.0000x reference)
//
#include <hip/hip_runtime.h>
#include <math.h>

#define H 1024
#define T 4096
#define B 16

// Kernel 1: v[b,h] = sum_d dec[d,b] * W[d,h]   (v = dec^T @ W, 16x1024)
// 16384 threads: gid = b*1024 + h. W loads coalesced across wave (consecutive h),
// dec loads wave-uniform (broadcast from cache).
__global__ void __launch_bounds__(256) proj_vec_kernel(
    const float* __restrict__ dec, const float* __restrict__ W,
    float* __restrict__ v)
{
    int gid = blockIdx.x * 256 + threadIdx.x;   // 0..16383
    int b = gid >> 10;
    int h = gid & (H - 1);
    float acc = 0.f;
    #pragma unroll 8
    for (int d = 0; d < H; ++d) {
        acc = fmaf(dec[d * B + b], W[d * H + h], acc);
    }
    v[b * H + h] = acc;
}

// Kernel 2: scores[b,t] = dot(v[b,:], enc[t,b,:]).
// One 64-lane wave per (t,b) pair; 4x float4 per lane = 1024 floats, fully
// coalesced (block of 4 waves covers 16 KiB contiguous of enc). HBM-bound:
// one 256 MiB pass over encoder_outputs.
__global__ void __launch_bounds__(256) scores_kernel(
    const float* __restrict__ v, const float* __restrict__ enc,
    float* __restrict__ scores)
{
    int wave = (int)((blockIdx.x * 256u + threadIdx.x) >> 6);  // 0..65535
    int lane = threadIdx.x & 63;
    int b = wave & (B - 1);
    int t = wave >> 4;
    const float4* ep = (const float4*)(enc + (size_t)t * (B * H) + (size_t)b * H);
    const float4* vp = (const float4*)(v + b * H);
    float acc = 0.f;
    #pragma unroll
    for (int i = 0; i < 4; ++i) {
        float4 e = ep[lane + i * 64];
        float4 w = vp[lane + i * 64];
        acc = fmaf(e.x, w.x, acc);
        acc = fmaf(e.y, w.y, acc);
        acc = fmaf(e.z, w.z, acc);
        acc = fmaf(e.w, w.w, acc);
    }
    #pragma unroll
    for (int off = 32; off > 0; off >>= 1)
        acc += __shfl_down(acc, off);
    if (lane == 0) scores[b * T + t] = acc;
}

// Kernel 3: row softmax, one block (256 threads = 4 waves) per b.
__global__ void __launch_bounds__(256) softmax_kernel(
    const float* __restrict__ scores, float* __restrict__ out)
{
    int b = blockIdx.x;
    int tid = threadIdx.x;
    __shared__ float red[8];
    const float4* rp = (const float4*)(scores + (size_t)b * T);
    float4 vals[4];
    float m = -INFINITY;
    #pragma unroll
    for (int i = 0; i < 4; ++i) {
        vals[i] = rp[tid + i * 256];
        m = fmaxf(m, fmaxf(fmaxf(vals[i].x, vals[i].y), fmaxf(vals[i].z, vals[i].w)));
    }
    #pragma unroll
    for (int off = 32; off > 0; off >>= 1)
        m = fmaxf(m, __shfl_down(m, off));
    if ((tid & 63) == 0) red[tid >> 6] = m;
    __syncthreads();
    m = fmaxf(fmaxf(red[0], red[1]), fmaxf(red[2], red[3]));

    float s = 0.f;
    #pragma unroll
    for (int i = 0; i < 4; ++i) {
        vals[i].x = __expf(vals[i].x - m);
        vals[i].y = __expf(vals[i].y - m);
        vals[i].z = __expf(vals[i].z - m);
        vals[i].w = __expf(vals[i].w - m);
        s += vals[i].x + vals[i].y + vals[i].z + vals[i].w;
    }
    #pragma unroll
    for (int off = 32; off > 0; off >>= 1)
        s += __shfl_down(s, off);
    if ((tid & 63) == 0) red[4 + (tid >> 6)] = s;
    __syncthreads();
    float inv = 1.f / (red[4] + red[5] + red[6] + red[7]);

    float4* op = (float4*)(out + (size_t)b * T);
    #pragma unroll
    for (int i = 0; i < 4; ++i) {
        float4 r;
        r.x = vals[i].x * inv;
        r.y = vals[i].y * inv;
        r.z = vals[i].z * inv;
        r.w = vals[i].w * inv;
        op[tid + i * 256] = r;
    }
}

extern "C" void kernel_launch(void* const* d_in, const int* in_sizes, int n_in,
                              void* d_out, int out_size, void* d_ws, size_t ws_size,
                              hipStream_t stream)
{
    const float* dec = (const float*)d_in[0];   // [H, B]
    const float* enc = (const float*)d_in[1];   // [T, B, H]
    const float* W   = (const float*)d_in[2];   // [H, H]
    float* out = (float*)d_out;                 // [B, T]

    float* v      = (float*)d_ws;               // B*H floats  (64 KiB)
    float* scores = v + B * H;                  // B*T floats  (256 KiB)

    proj_vec_kernel<<<(B * H) / 256, 256, 0, stream>>>(dec, W, v);
    scores_kernel<<<(T * B) / 4, 256, 0, stream>>>(v, enc, scores);
    softmax_kernel<<<B, 256, 0, stream>>>(scores, out);
}

// Round 3
// 53.066 us; speedup vs baseline: 1.8553x; 1.8553x over previous
//
#include <hip/hip_runtime.h>
#include <math.h>

#define H 1024
#define T 4096
#define B 16

typedef float f4 __attribute__((ext_vector_type(4)));

// Kernel 1: v[b,h] = sum_d dec[d,b] * W[d,h]   (v = dec^T @ W, 16x1024)
// Grid: 256 blocks = 16 b x 16 h-tiles (64 h each). Block: 256 thr =
// 16 dc (d-split) x 16 h4 (float4 h-groups). Each thread: 64 iters of
// float4 W loads (coalesced 256B per 16-lane group), LDS tree-reduce
// over dc. All 256 CUs busy; ~64 loads/thread -> latency amortized.
__global__ void __launch_bounds__(256) proj_vec_kernel(
    const float* __restrict__ dec, const float* __restrict__ W,
    float* __restrict__ v)
{
    int b     = blockIdx.x >> 4;
    int htile = blockIdx.x & 15;
    int h4    = threadIdx.x & 15;   // 0..15: which float4 within the 64-h tile
    int dc    = threadIdx.x >> 4;   // 0..15: d-chunk of 64
    int h4base = htile * 16;        // in float4 units

    const f4* Wp = (const f4*)W;   // Wp[d*(H/4) + h4idx]
    f4 acc = {0.f, 0.f, 0.f, 0.f};
    int d0 = dc * 64;
    #pragma unroll 8
    for (int i = 0; i < 64; ++i) {
        int d = d0 + i;
        float s = dec[d * B + b];
        f4 w = Wp[d * (H / 4) + h4base + h4];
        acc += s * w;
    }

    __shared__ f4 red[256];
    red[threadIdx.x] = acc;
    __syncthreads();
    #pragma unroll
    for (int s = 8; s > 0; s >>= 1) {
        if (dc < s) {
            f4 m = red[dc * 16 + h4] + red[(dc + s) * 16 + h4];
            red[dc * 16 + h4] = m;
        }
        __syncthreads();
    }
    if (dc == 0) {
        ((f4*)(v + b * H))[h4base + h4] = red[h4];
    }
}

// Kernel 2: scores[b,t] = dot(v[b,:], enc[t,b,:]).
// One 64-lane wave per (t,b); 4x float4 nontemporal loads per lane (enc is
// single-pass, skip L2 pollution). Block of 4 waves covers 16 KiB contiguous.
__global__ void __launch_bounds__(256) scores_kernel(
    const float* __restrict__ v, const float* __restrict__ enc,
    float* __restrict__ scores)
{
    int wave = (int)((blockIdx.x * 256u + threadIdx.x) >> 6);  // 0..65535
    int lane = threadIdx.x & 63;
    int b = wave & (B - 1);
    int t = wave >> 4;
    const f4* ep = (const f4*)(enc + (size_t)t * (B * H) + (size_t)b * H);
    const f4* vp = (const f4*)(v + b * H);
    float acc = 0.f;
    #pragma unroll
    for (int i = 0; i < 4; ++i) {
        f4 e = __builtin_nontemporal_load(&ep[lane + i * 64]);
        f4 w = vp[lane + i * 64];
        acc = fmaf(e.x, w.x, acc);
        acc = fmaf(e.y, w.y, acc);
        acc = fmaf(e.z, w.z, acc);
        acc = fmaf(e.w, w.w, acc);
    }
    #pragma unroll
    for (int off = 32; off > 0; off >>= 1)
        acc += __shfl_down(acc, off);
    if (lane == 0) scores[b * T + t] = acc;
}

// Kernel 3: row softmax, one block (256 threads = 4 waves) per b.
__global__ void __launch_bounds__(256) softmax_kernel(
    const float* __restrict__ scores, float* __restrict__ out)
{
    int b = blockIdx.x;
    int tid = threadIdx.x;
    __shared__ float red[8];
    const f4* rp = (const f4*)(scores + (size_t)b * T);
    f4 vals[4];
    float m = -INFINITY;
    #pragma unroll
    for (int i = 0; i < 4; ++i) {
        vals[i] = rp[tid + i * 256];
        m = fmaxf(m, fmaxf(fmaxf(vals[i].x, vals[i].y), fmaxf(vals[i].z, vals[i].w)));
    }
    #pragma unroll
    for (int off = 32; off > 0; off >>= 1)
        m = fmaxf(m, __shfl_down(m, off));
    if ((tid & 63) == 0) red[tid >> 6] = m;
    __syncthreads();
    m = fmaxf(fmaxf(red[0], red[1]), fmaxf(red[2], red[3]));

    float s = 0.f;
    #pragma unroll
    for (int i = 0; i < 4; ++i) {
        vals[i].x = __expf(vals[i].x - m);
        vals[i].y = __expf(vals[i].y - m);
        vals[i].z = __expf(vals[i].z - m);
        vals[i].w = __expf(vals[i].w - m);
        s += vals[i].x + vals[i].y + vals[i].z + vals[i].w;
    }
    #pragma unroll
    for (int off = 32; off > 0; off >>= 1)
        s += __shfl_down(s, off);
    if ((tid & 63) == 0) red[4 + (tid >> 6)] = s;
    __syncthreads();
    float inv = 1.f / (red[4] + red[5] + red[6] + red[7]);

    f4* op = (f4*)(out + (size_t)b * T);
    #pragma unroll
    for (int i = 0; i < 4; ++i) {
        f4 r = vals[i] * inv;
        op[tid + i * 256] = r;
    }
}

extern "C" void kernel_launch(void* const* d_in, const int* in_sizes, int n_in,
                              void* d_out, int out_size, void* d_ws, size_t ws_size,
                              hipStream_t stream)
{
    const float* dec = (const float*)d_in[0];   // [H, B]
    const float* enc = (const float*)d_in[1];   // [T, B, H]
    const float* W   = (const float*)d_in[2];   // [H, H]
    float* out = (float*)d_out;                 // [B, T]

    float* v      = (float*)d_ws;               // B*H floats  (64 KiB)
    float* scores = v + B * H;                  // B*T floats  (256 KiB)

    proj_vec_kernel<<<256, 256, 0, stream>>>(dec, W, v);
    scores_kernel<<<(T * B) / 4, 256, 0, stream>>>(v, enc, scores);
    softmax_kernel<<<B, 256, 0, stream>>>(scores, out);
}